// Round 8
// baseline (195.833 us; speedup 1.0000x reference)
//
#include <hip/hip_runtime.h>

// B=8, L=512, D=512, H=8. Q/K GEMMs: M=4096, N=4096, K=512 -- now fp8-e4m3 MFMA
// (16x16x32_fp8_fp8 at bf16 rate but half the LDS/HBM bytes). W pre-scaled x16 so
// Q' = 16*(X@W + b) is stored fp8 in a healthy range; scores rescale by 1/(256*sqrt(512)).
// V path (all f32): P' = softmax + 63.875; Y = sum_l P'*Xv; out = Y @ Wv + c*bv.

using f32x4 = __attribute__((ext_vector_type(4))) float;

__device__ __forceinline__ float bflo(unsigned int u) {
    union { unsigned int u; float f; } c; c.u = u << 16; return c.f;
}

#define GLOAD16(gp, lp) __builtin_amdgcn_global_load_lds( \
    (const __attribute__((address_space(1))) unsigned int*)(gp), \
    (__attribute__((address_space(3))) unsigned int*)(lp), 16, 0, 0)

// ---------------- kernel 1: prep = convert Xq/Xk -> fp8 (z=0,1); transpose W*16 -> fp8 (z=2,3)
__global__ __launch_bounds__(256) void prep(
    const float* __restrict__ x0, const float* __restrict__ x1,
    unsigned char* __restrict__ o0, unsigned char* __restrict__ o1,
    const float* __restrict__ w0, const float* __restrict__ w1,
    unsigned char* __restrict__ t0, unsigned char* __restrict__ t1)
{
    const int z = blockIdx.z;
    if (z < 2) {
        const float* src = (z == 0) ? x0 : x1;
        unsigned char* dst = (z == 0) ? o0 : o1;
        int i = (blockIdx.x * 256 + threadIdx.x) * 8;
        if (i < 2097152) {
            float4 a = *(const float4*)(src + i);
            float4 b = *(const float4*)(src + i + 4);
            uint2 u;
            u.x = __builtin_amdgcn_cvt_pk_fp8_f32(a.x, a.y, 0u, false);
            u.x = __builtin_amdgcn_cvt_pk_fp8_f32(a.z, a.w, u.x, true);
            u.y = __builtin_amdgcn_cvt_pk_fp8_f32(b.x, b.y, 0u, false);
            u.y = __builtin_amdgcn_cvt_pk_fp8_f32(b.z, b.w, u.y, true);
            *(uint2*)(dst + i) = u;
        }
    } else {
        const float* W = (z == 2) ? w0 : w1;
        unsigned char* T = (z == 2) ? t0 : t1;
        __shared__ float tile[32][33];
        const int n0 = (blockIdx.x & 127) * 32, k0 = (blockIdx.x >> 7) * 32;
        const int tx = threadIdx.x & 31, ty = threadIdx.x >> 5;   // (32, 8)
        #pragma unroll
        for (int j = 0; j < 32; j += 8)
            tile[ty + j][tx] = W[(size_t)(k0 + ty + j) * 4096 + n0 + tx];
        __syncthreads();
        // thread -> (n = ty*4 + tx>>3, kq = tx&7): one u32 of 4 fp8 (W x16)
        const int n = ty * 4 + (tx >> 3), kq = tx & 7;
        unsigned int pk = __builtin_amdgcn_cvt_pk_fp8_f32(
            16.f * tile[kq * 4 + 0][n], 16.f * tile[kq * 4 + 1][n], 0u, false);
        pk = __builtin_amdgcn_cvt_pk_fp8_f32(
            16.f * tile[kq * 4 + 2][n], 16.f * tile[kq * 4 + 3][n], pk, true);
        *(unsigned int*)(T + (size_t)(n0 + n) * 512 + k0 + kq * 4) = pk;
    }
}

// ---------------- kernel 2: 256^2 8-phase FP8 GEMM, fp8 coalesced epilogue -----------
// LDS 64 KiB: As 2x16K | Bs 2x16K (rows 64B, granule-XOR g^=row&3). 1 GLOAD per phase.
__global__ __launch_bounds__(512, 4) void gemm_bt256(
    const unsigned char* __restrict__ a0, const unsigned char* __restrict__ a1,
    const unsigned char* __restrict__ w0, const unsigned char* __restrict__ w1,
    const float* __restrict__ b0, const float* __restrict__ b1,
    unsigned char* __restrict__ c0, unsigned char* __restrict__ c1)
{
    const unsigned char* A;  const unsigned char* Bt; const float* bias; unsigned char* C;
    if (blockIdx.z == 0) { A = a0; Bt = w0; bias = b0; C = c0; }
    else                 { A = a1; Bt = w1; bias = b1; C = c1; }

    __shared__ __align__(16) unsigned char SH[65536];

    const int tid  = threadIdx.x;
    const int lane = tid & 63;
    const int wid  = tid >> 6;
    const int wr   = wid >> 2;
    const int wn   = wid & 3;
    const int linb = blockIdx.y * 16 + blockIdx.x;
    const int swz  = (linb & 7) * 32 + (linb >> 3);
    const int bx   = (swz >> 6) * 4 + (swz & 3);
    const int by   = (swz >> 2) & 15;
    const int row0 = by * 256;
    const int n0   = bx * 256;

    // staging: each GLOAD16 = 16 rows x 64B; lane -> row lane>>2, granule (lane&3)^((lane>>2)&3)
    const int sg4 = (lane & 3) ^ ((lane >> 2) & 3);
    const unsigned char* gA = A  + (size_t)(row0 + wid * 16 + (lane >> 2)) * 512 + sg4 * 16;
    const unsigned char* gB = Bt + (size_t)(n0   + wid * 16 + (lane >> 2)) * 512 + sg4 * 16;

#define STAGE_A(gp, buf, half, trel)                                              \
    GLOAD16((gp) + (half) * 128 * 512 + (trel) * 64,                              \
            SH + (buf) * 16384 + ((half) * 128 + wid * 16) * 64)
#define STAGE_B(gp, buf, half, trel)                                              \
    GLOAD16((gp) + (half) * 128 * 512 + (trel) * 64,                              \
            SH + 32768 + (buf) * 16384 + ((half) * 128 + wid * 16) * 64)

    // frag reads: row r, k-bytes s*32+ko*8; granule g = s*2+(ko>>1), swz g^(r&3)
    // r&3 == lane&3 for all frag rows; ko = lane>>4.
    const int swo0 = ((((lane >> 5)    ) ^ (lane & 3)) << 4) + ((lane >> 4) & 1) * 8;
    const int swo1 = (((2 + (lane >> 5)) ^ (lane & 3)) << 4) + ((lane >> 4) & 1) * 8;
    const char* bA0 = (const char*)SH + (wr * 128 + (lane & 15)) * 64 + swo0;
    const char* bA1 = (const char*)SH + (wr * 128 + (lane & 15)) * 64 + swo1;
    const char* bB0 = (const char*)SH + 32768 + (wn * 64 + (lane & 15)) * 64 + swo0;
    const char* bB1 = (const char*)SH + 32768 + (wn * 64 + (lane & 15)) * 64 + swo1;

#define LD_A(c, m, s) (*(const long long*)(((s) ? bA1 : bA0) + (c) * 16384 + (m) * 1024))
#define LD_B(c, n, s) (*(const long long*)(((s) ? bB1 : bB0) + (c) * 16384 + (n) * 1024))

#define BAR() __builtin_amdgcn_s_barrier()
#define VMC2() asm volatile("s_waitcnt vmcnt(2)" ::: "memory")
#define VMC0() asm volatile("s_waitcnt vmcnt(0)" ::: "memory")

    f32x4 acc[8][4];
    #pragma unroll
    for (int m = 0; m < 8; ++m)
        #pragma unroll
        for (int n = 0; n < 4; ++n)
            acc[m][n] = (f32x4){0.f, 0.f, 0.f, 0.f};

    long long bfr[4][2];
    long long fa0, fa1, fa2, fa3;

#define LDA_Q(c, q) { fa0 = LD_A(c, 2*(q), 0); fa1 = LD_A(c, 2*(q), 1);           \
                      fa2 = LD_A(c, 2*(q)+1, 0); fa3 = LD_A(c, 2*(q)+1, 1); }
#define LDB_ALL(c) { _Pragma("unroll") for (int n = 0; n < 4; ++n) {              \
                       bfr[n][0] = LD_B(c, n, 0); bfr[n][1] = LD_B(c, n, 1); } }
#define MFMA_Q(q) { __builtin_amdgcn_s_setprio(1);                                \
    _Pragma("unroll") for (int n = 0; n < 4; ++n) {                               \
      acc[2*(q)][n]   = __builtin_amdgcn_mfma_f32_16x16x32_fp8_fp8(bfr[n][0], fa0, acc[2*(q)][n],   0,0,0); \
      acc[2*(q)][n]   = __builtin_amdgcn_mfma_f32_16x16x32_fp8_fp8(bfr[n][1], fa1, acc[2*(q)][n],   0,0,0); \
      acc[2*(q)+1][n] = __builtin_amdgcn_mfma_f32_16x16x32_fp8_fp8(bfr[n][0], fa2, acc[2*(q)+1][n], 0,0,0); \
      acc[2*(q)+1][n] = __builtin_amdgcn_mfma_f32_16x16x32_fp8_fp8(bfr[n][1], fa3, acc[2*(q)+1][n], 0,0,0); } \
    __builtin_amdgcn_s_setprio(0); }

    // prologue: buf0.B(t0), buf0.A(t0), buf1.B(t1) -> 6 issues; first 4 = tile0
    STAGE_B(gB, 0, 0, 0); STAGE_B(gB, 0, 1, 0);
    STAGE_A(gA, 0, 0, 0); STAGE_A(gA, 0, 1, 0);
    STAGE_B(gB, 1, 0, 1); STAGE_B(gB, 1, 1, 1);
    VMC2();
    BAR();

    const unsigned char* gAt = gA;   // tile 2i base
    const unsigned char* gBt = gB;
    for (int i = 0; i < 4; ++i) {
        const bool s23 = (i < 3);

        LDA_Q(0, 0); LDB_ALL(0);
        STAGE_A(gAt, 1, 0, 1);
        BAR(); MFMA_Q(0); BAR();

        LDA_Q(0, 1);
        STAGE_A(gAt, 1, 1, 1);
        BAR(); MFMA_Q(1); BAR();

        LDA_Q(0, 2);
        if (s23) STAGE_B(gBt, 0, 0, 2);
        BAR(); MFMA_Q(2); BAR();

        LDA_Q(0, 3);
        if (s23) STAGE_B(gBt, 0, 1, 2);
        BAR(); MFMA_Q(3);
        if (s23) { VMC2(); } else { VMC0(); }
        BAR();

        LDA_Q(1, 0); LDB_ALL(1);
        if (s23) STAGE_A(gAt, 0, 0, 2);
        BAR(); MFMA_Q(0); BAR();

        LDA_Q(1, 1);
        if (s23) STAGE_A(gAt, 0, 1, 2);
        BAR(); MFMA_Q(1); BAR();

        LDA_Q(1, 2);
        if (s23) STAGE_B(gBt, 1, 0, 3);
        BAR(); MFMA_Q(2); BAR();

        LDA_Q(1, 3);
        if (s23) STAGE_B(gBt, 1, 1, 3);
        BAR(); MFMA_Q(3);
        if (s23) { VMC2(); }
        BAR();

        gAt += 128; gBt += 128;
    }

    // ---- epilogue: acc(+16*bias) -> swizzled fp8 LDS tile (256x256 = 64 KB) -> C ----
    {
        const int q  = lane >> 4;
        const int tr = wr * 128 + (lane & 15);
        #pragma unroll
        for (int n = 0; n < 4; ++n) {
            float4 bb = *(const float4*)(bias + n0 + wn * 64 + n * 16 + q * 4);
            const int g16 = wn * 4 + n;
            #pragma unroll
            for (int m = 0; m < 8; ++m) {
                const int trm = tr + m * 16;
                unsigned int pk = __builtin_amdgcn_cvt_pk_fp8_f32(
                    acc[m][n][0] + 16.f * bb.x, acc[m][n][1] + 16.f * bb.y, 0u, false);
                pk = __builtin_amdgcn_cvt_pk_fp8_f32(
                    acc[m][n][2] + 16.f * bb.z, acc[m][n][3] + 16.f * bb.w, pk, true);
                *(unsigned int*)(SH + trm * 256 + ((g16 ^ (trm & 15)) << 4) + q * 4) = pk;
            }
        }
        BAR();
        #pragma unroll
        for (int it = 0; it < 8; ++it) {
            const int f = it * 512 + tid;
            const int rr = f >> 4, gg = f & 15;
            uint4 v = *(const uint4*)(SH + rr * 256 + ((gg ^ (rr & 15)) << 4));
            *(uint4*)(C + (size_t)(row0 + rr) * 4096 + gg * 16 + n0) = v;
        }
    }
#undef STAGE_A
#undef STAGE_B
#undef LD_A
#undef LD_B
}

// ---------------- kernel 3: fp8-MFMA scores + softmax + pb-partials ------------------
__global__ __launch_bounds__(256) void mfscores(const unsigned char* __restrict__ Q,
                                                const unsigned char* __restrict__ K,
                                                float* __restrict__ P,
                                                float* __restrict__ pbpart)
{
    __shared__ float Pl[8 * 64];
    const int b = blockIdx.x, lc = blockIdx.y;       // (8, 64)
    const int tid = threadIdx.x, lane = tid & 63, w = tid >> 6;
    const int l0 = lc * 8;

    const int colr = lane & 15;
    const int ko   = lane >> 4;
    const int la   = l0 + w * 2 + (colr >> 3);
    const int hh   = colr & 7;
    const unsigned char* qrow = Q + (size_t)(b * 512 + la) * 4096 + hh * 512 + ko * 8;
    const unsigned char* krow = K + (size_t)(b * 512 + la) * 4096 + hh * 512 + ko * 8;

    f32x4 acc = (f32x4){0.f, 0.f, 0.f, 0.f};
    #pragma unroll
    for (int kt = 0; kt < 16; ++kt) {
        long long av = *(const long long*)(qrow + kt * 32);
        long long bv = *(const long long*)(krow + kt * 32);
        acc = __builtin_amdgcn_mfma_f32_16x16x32_fp8_fp8(av, bv, acc, 0, 0, 0);
    }

    const int lpr = ko >> 1;
    const int lpc = (lane >> 3) & 1;
    #pragma unroll
    for (int r = 0; r < 4; ++r) {
        float s = acc[r] * 1.7263349150062e-4f;   // 1/(256*sqrt(512)) -- Q',K' are x16
        float m = s;
        m = fmaxf(m, __shfl_xor(m, 1));
        m = fmaxf(m, __shfl_xor(m, 2));
        m = fmaxf(m, __shfl_xor(m, 4));
        float e = __expf(s - m);
        float ss = e;
        ss += __shfl_xor(ss, 1);
        ss += __shfl_xor(ss, 2);
        ss += __shfl_xor(ss, 4);
        float p = e / ss + 63.875f;               // fold uniform part
        if (lpr == lpc)
            Pl[(w * 2 + lpr) * 64 + ((ko & 1) * 4 + r) * 8 + (lane & 7)] = p;
    }
    __syncthreads();

    {
        const int l = tid >> 5, off = (tid & 31) * 2;
        float2 v = *(const float2*)&Pl[l * 64 + off];
        *(float2*)(P + (size_t)(b * 512 + l0 + l) * 64 + off) = v;
    }
    if (tid < 64) {
        float s = 0.f;
        #pragma unroll
        for (int l = 0; l < 8; ++l) s += Pl[l * 64 + tid];
        pbpart[((size_t)b * 64 + lc) * 64 + tid] = s;
    }
}

// ---------------- kernel 4: ypart[lc,b,hg,d] = sum_{l in chunk} P' * Xv --------------
__global__ __launch_bounds__(256) void ykern(const float* __restrict__ P,
                                             const float* __restrict__ Xv,
                                             float* __restrict__ ypart)
{
    __shared__ float Pl[128 * 64];
    __shared__ float Xl[128 * 64];
    const int b = blockIdx.x, dt = blockIdx.y, lc = blockIdx.z;
    const int tid = threadIdx.x;
    const int tm = tid & 15, te = tid >> 4;

    const float* Pg = P + ((size_t)b * 512 + lc * 128) * 64;
    #pragma unroll
    for (int i = 0; i < 8; ++i)
        *(float4*)&Pl[(i * 256 + tid) * 4] = *(const float4*)(Pg + (size_t)(i * 256 + tid) * 4);
    const float* Xg = Xv + ((size_t)b * 512 + lc * 128) * 512 + dt * 64;
    #pragma unroll
    for (int i = 0; i < 8; ++i) {
        int flat = i * 256 + tid;
        int r = flat >> 4, q = flat & 15;
        *(float4*)&Xl[r * 64 + q * 4] = *(const float4*)(Xg + (size_t)r * 512 + q * 4);
    }
    __syncthreads();

    float4 acc[4];
    #pragma unroll
    for (int i = 0; i < 4; ++i) acc[i] = make_float4(0.f, 0.f, 0.f, 0.f);

    for (int l = 0; l < 128; ++l) {
        float4 pv = *(const float4*)&Pl[l * 64 + tm * 4];
        float4 xv = *(const float4*)&Xl[l * 64 + te * 4];
        acc[0].x += pv.x * xv.x; acc[0].y += pv.x * xv.y; acc[0].z += pv.x * xv.z; acc[0].w += pv.x * xv.w;
        acc[1].x += pv.y * xv.x; acc[1].y += pv.y * xv.y; acc[1].z += pv.y * xv.z; acc[1].w += pv.y * xv.w;
        acc[2].x += pv.z * xv.x; acc[2].y += pv.z * xv.y; acc[2].z += pv.z * xv.z; acc[2].w += pv.z * xv.w;
        acc[3].x += pv.w * xv.x; acc[3].y += pv.w * xv.y; acc[3].z += pv.w * xv.z; acc[3].w += pv.w * xv.w;
    }
    #pragma unroll
    for (int i = 0; i < 4; ++i)
        *(float4*)&ypart[(((size_t)lc * 8 + b) * 64 + tm * 4 + i) * 512 + dt * 64 + te * 4] = acc[i];
}

// ---------------- kernel 5: split-K vgemm (yreduce fused into A-stage) ---------------
__global__ __launch_bounds__(256) void vgemm(const float* __restrict__ ypart,
                                             const float* __restrict__ Wv,
                                             float* __restrict__ partial)
{
    __shared__ float Al[64 * 64];
    __shared__ float Bl[64 * 64];
    const int et = blockIdx.x, kc = blockIdx.y;
    const int g = kc >> 3, d0 = (kc & 7) * 64, e0 = et * 64;
    const int tid = threadIdx.x;
    const int tm = tid & 15, te = tid >> 4;

    #pragma unroll
    for (int i = 0; i < 4; ++i) {
        int flat = i * 256 + tid;
        int bh = flat >> 4, dq = flat & 15;
        int yrow = (bh >> 3) * 64 + (bh & 7) * 8 + g;
        size_t base = ((size_t)(yrow >> 6) * 64 + (yrow & 63)) * 512 + d0 + dq * 4;
        float4 v = *(const float4*)(ypart + base);
        #pragma unroll
        for (int lc = 1; lc < 4; ++lc) {
            float4 t = *(const float4*)(ypart + (size_t)lc * 262144 + base);
            v.x += t.x; v.y += t.y; v.z += t.z; v.w += t.w;
        }
        *(float4*)&Al[bh * 64 + ((dq ^ (bh >> 2)) << 2)] = v;
    }
    #pragma unroll
    for (int i = 0; i < 4; ++i) {
        int flat = i * 256 + tid;
        int kk = flat >> 4, eq = flat & 15;
        *(float4*)&Bl[kk * 64 + eq * 4] =
            *(const float4*)(Wv + (size_t)(d0 + kk) * 4096 + g * 512 + e0 + eq * 4);
    }
    __syncthreads();

    float4 acc[4];
    #pragma unroll
    for (int j = 0; j < 4; ++j) acc[j] = make_float4(0.f, 0.f, 0.f, 0.f);

    for (int k = 0; k < 64; ++k) {
        float4 b4 = *(const float4*)&Bl[k * 64 + te * 4];
        const int gcol = (((k >> 2) ^ tm) << 2) + (k & 3);
        #pragma unroll
        for (int j = 0; j < 4; ++j) {
            float a = Al[(tm * 4 + j) * 64 + gcol];
            acc[j].x += a * b4.x; acc[j].y += a * b4.y;
            acc[j].z += a * b4.z; acc[j].w += a * b4.w;
        }
    }
    #pragma unroll
    for (int j = 0; j < 4; ++j)
        *(float4*)&partial[(size_t)kc * 32768 + (tm * 4 + j) * 512 + e0 + te * 4] = acc[j];
}

// ---------------- kernel 6: finalize: out = sum_kc partial + sum_g c*bv --------------
__global__ __launch_bounds__(256) void finalize(const float* __restrict__ partial,
                                                const float* __restrict__ pbpart,
                                                const float* __restrict__ bv,
                                                float* __restrict__ out)
{
    __shared__ float csh[8];
    const int blk = blockIdx.x;
    const int tid = threadIdx.x;
    const int b = blk >> 4, h = (blk >> 1) & 7;
    const int e = (blk & 1) * 256 + tid;

    if (tid < 8) {
        float s = 0.f;
        #pragma unroll 8
        for (int lcc = 0; lcc < 64; ++lcc)
            s += pbpart[((size_t)b * 64 + lcc) * 64 + h * 8 + tid];
        csh[tid] = s;
    }
    __syncthreads();

    const int i = ((b * 8 + h) << 9) + e;
    float s = 0.f;
    #pragma unroll
    for (int kc = 0; kc < 64; ++kc) s += partial[(size_t)kc * 32768 + i];
    float bt = 0.f;
    #pragma unroll
    for (int g = 0; g < 8; ++g) bt += csh[g] * bv[g * 512 + e];
    out[i] = s + bt;
}

extern "C" void kernel_launch(void* const* d_in, const int* in_sizes, int n_in,
                              void* d_out, int out_size, void* d_ws, size_t ws_size,
                              hipStream_t stream)
{
    const float* queries = (const float*)d_in[0];
    const float* keys    = (const float*)d_in[1];
    const float* values  = (const float*)d_in[2];
    const float* Wq      = (const float*)d_in[3];
    const float* bq      = (const float*)d_in[4];
    const float* Wk      = (const float*)d_in[5];
    const float* bk      = (const float*)d_in[6];
    const float* Wv      = (const float*)d_in[7];
    const float* bv      = (const float*)d_in[8];

    unsigned char* xq  = (unsigned char*)d_ws;          // 2 MB each
    unsigned char* xk  = xq  + (1u << 21);
    unsigned char* wtq = xk  + (1u << 21);
    unsigned char* wtk = wtq + (1u << 21);
    unsigned char* Q   = wtk + (1u << 21);              // 16 MB each
    unsigned char* Kb  = Q   + (1u << 24);
    float* P      = (float*)(Kb + (1u << 24));
    float* pbpart = P + 262144;
    float* ypart  = pbpart + 32768;
    float* part   = ypart + 4 * 262144;

    prep<<<dim3(2048, 1, 4), 256, 0, stream>>>(queries, keys, xq, xk, Wq, Wk, wtq, wtk);
    gemm_bt256<<<dim3(16, 16, 2), 512, 0, stream>>>(xq, xk, wtq, wtk, bq, bk, Q, Kb);
    mfscores<<<dim3(8, 64), 256, 0, stream>>>(Q, Kb, P, pbpart);
    ykern<<<dim3(8, 8, 4), 256, 0, stream>>>(P, values, ypart);
    vgemm<<<dim3(8, 64), 256, 0, stream>>>(ypart, Wv, part);
    finalize<<<dim3(128), 256, 0, stream>>>(part, pbpart, bv, (float*)d_out);
}

// Round 9
// 88.757 us; speedup vs baseline: 2.2064x; 2.2064x over previous
//
#include <hip/hip_runtime.h>

// B=8, L=512, D=512, H=8. Q/K GEMMs: M=4096, N=4096, K=512 -- fp8-e4m3 MFMA
// (16x16x32_fp8_fp8 at bf16 rate but half the LDS/HBM bytes). W pre-scaled x16 so
// Q' = 16*(X@W + b) is stored fp8 in a healthy range; scores rescale by 1/(256*sqrt(512)).
// V path (all f32): P' = softmax + 63.875; Y = sum_l P'*Xv; out = Y @ Wv + c*bv.
// R9 fix: __launch_bounds__(512) -- the (512,4) min-occupancy hint forced a 128-reg
// budget -> scratch spill (R8: VGPR=64, 464 MB scratch WRITE, 196 us).

using f32x4 = __attribute__((ext_vector_type(4))) float;

__device__ __forceinline__ float bflo(unsigned int u) {
    union { unsigned int u; float f; } c; c.u = u << 16; return c.f;
}

#define GLOAD16(gp, lp) __builtin_amdgcn_global_load_lds( \
    (const __attribute__((address_space(1))) unsigned int*)(gp), \
    (__attribute__((address_space(3))) unsigned int*)(lp), 16, 0, 0)

// ---------------- kernel 1: prep = convert Xq/Xk -> fp8 (z=0,1); transpose W*16 -> fp8 (z=2,3)
__global__ __launch_bounds__(256) void prep(
    const float* __restrict__ x0, const float* __restrict__ x1,
    unsigned char* __restrict__ o0, unsigned char* __restrict__ o1,
    const float* __restrict__ w0, const float* __restrict__ w1,
    unsigned char* __restrict__ t0, unsigned char* __restrict__ t1)
{
    const int z = blockIdx.z;
    if (z < 2) {
        const float* src = (z == 0) ? x0 : x1;
        unsigned char* dst = (z == 0) ? o0 : o1;
        int i = (blockIdx.x * 256 + threadIdx.x) * 8;
        if (i < 2097152) {
            float4 a = *(const float4*)(src + i);
            float4 b = *(const float4*)(src + i + 4);
            uint2 u;
            u.x = __builtin_amdgcn_cvt_pk_fp8_f32(a.x, a.y, 0u, false);
            u.x = __builtin_amdgcn_cvt_pk_fp8_f32(a.z, a.w, u.x, true);
            u.y = __builtin_amdgcn_cvt_pk_fp8_f32(b.x, b.y, 0u, false);
            u.y = __builtin_amdgcn_cvt_pk_fp8_f32(b.z, b.w, u.y, true);
            *(uint2*)(dst + i) = u;
        }
    } else {
        const float* W = (z == 2) ? w0 : w1;
        unsigned char* T = (z == 2) ? t0 : t1;
        __shared__ float tile[32][33];
        const int n0 = (blockIdx.x & 127) * 32, k0 = (blockIdx.x >> 7) * 32;
        const int tx = threadIdx.x & 31, ty = threadIdx.x >> 5;   // (32, 8)
        #pragma unroll
        for (int j = 0; j < 32; j += 8)
            tile[ty + j][tx] = W[(size_t)(k0 + ty + j) * 4096 + n0 + tx];
        __syncthreads();
        // thread -> (n = ty*4 + tx>>3, kq = tx&7): one u32 of 4 fp8 (W x16)
        const int n = ty * 4 + (tx >> 3), kq = tx & 7;
        unsigned int pk = __builtin_amdgcn_cvt_pk_fp8_f32(
            16.f * tile[kq * 4 + 0][n], 16.f * tile[kq * 4 + 1][n], 0u, false);
        pk = __builtin_amdgcn_cvt_pk_fp8_f32(
            16.f * tile[kq * 4 + 2][n], 16.f * tile[kq * 4 + 3][n], pk, true);
        *(unsigned int*)(T + (size_t)(n0 + n) * 512 + k0 + kq * 4) = pk;
    }
}

// ---------------- kernel 2: 256^2 8-phase FP8 GEMM, fp8 coalesced epilogue -----------
// LDS 64 KiB: As 2x16K | Bs 2x16K (rows 64B, granule-XOR g^=row&3). 1 GLOAD per phase.
__global__ __launch_bounds__(512) void gemm_bt256(
    const unsigned char* __restrict__ a0, const unsigned char* __restrict__ a1,
    const unsigned char* __restrict__ w0, const unsigned char* __restrict__ w1,
    const float* __restrict__ b0, const float* __restrict__ b1,
    unsigned char* __restrict__ c0, unsigned char* __restrict__ c1)
{
    const unsigned char* A;  const unsigned char* Bt; const float* bias; unsigned char* C;
    if (blockIdx.z == 0) { A = a0; Bt = w0; bias = b0; C = c0; }
    else                 { A = a1; Bt = w1; bias = b1; C = c1; }

    __shared__ __align__(16) unsigned char SH[65536];

    const int tid  = threadIdx.x;
    const int lane = tid & 63;
    const int wid  = tid >> 6;
    const int wr   = wid >> 2;
    const int wn   = wid & 3;
    const int linb = blockIdx.y * 16 + blockIdx.x;
    const int swz  = (linb & 7) * 32 + (linb >> 3);
    const int bx   = (swz >> 6) * 4 + (swz & 3);
    const int by   = (swz >> 2) & 15;
    const int row0 = by * 256;
    const int n0   = bx * 256;

    // staging: each GLOAD16 = 16 rows x 64B; lane -> row lane>>2, granule (lane&3)^((lane>>2)&3)
    const int sg4 = (lane & 3) ^ ((lane >> 2) & 3);
    const unsigned char* gA = A  + (size_t)(row0 + wid * 16 + (lane >> 2)) * 512 + sg4 * 16;
    const unsigned char* gB = Bt + (size_t)(n0   + wid * 16 + (lane >> 2)) * 512 + sg4 * 16;

#define STAGE_A(gp, buf, half, trel)                                              \
    GLOAD16((gp) + (half) * 128 * 512 + (trel) * 64,                              \
            SH + (buf) * 16384 + ((half) * 128 + wid * 16) * 64)
#define STAGE_B(gp, buf, half, trel)                                              \
    GLOAD16((gp) + (half) * 128 * 512 + (trel) * 64,                              \
            SH + 32768 + (buf) * 16384 + ((half) * 128 + wid * 16) * 64)

    // frag reads: row r, k-bytes s*32+ko*8; granule g = s*2+(ko>>1), swz g^(r&3)
    // r&3 == lane&3 for all frag rows; ko = lane>>4.
    const int swo0 = ((((lane >> 5)    ) ^ (lane & 3)) << 4) + ((lane >> 4) & 1) * 8;
    const int swo1 = (((2 + (lane >> 5)) ^ (lane & 3)) << 4) + ((lane >> 4) & 1) * 8;
    const char* bA0 = (const char*)SH + (wr * 128 + (lane & 15)) * 64 + swo0;
    const char* bA1 = (const char*)SH + (wr * 128 + (lane & 15)) * 64 + swo1;
    const char* bB0 = (const char*)SH + 32768 + (wn * 64 + (lane & 15)) * 64 + swo0;
    const char* bB1 = (const char*)SH + 32768 + (wn * 64 + (lane & 15)) * 64 + swo1;

#define LD_A(c, m, s) (*(const long long*)(((s) ? bA1 : bA0) + (c) * 16384 + (m) * 1024))
#define LD_B(c, n, s) (*(const long long*)(((s) ? bB1 : bB0) + (c) * 16384 + (n) * 1024))

#define BAR() __builtin_amdgcn_s_barrier()
#define VMC2() asm volatile("s_waitcnt vmcnt(2)" ::: "memory")
#define VMC0() asm volatile("s_waitcnt vmcnt(0)" ::: "memory")

    f32x4 acc[8][4];
    #pragma unroll
    for (int m = 0; m < 8; ++m)
        #pragma unroll
        for (int n = 0; n < 4; ++n)
            acc[m][n] = (f32x4){0.f, 0.f, 0.f, 0.f};

    long long bfr[4][2];
    long long fa0, fa1, fa2, fa3;

#define LDA_Q(c, q) { fa0 = LD_A(c, 2*(q), 0); fa1 = LD_A(c, 2*(q), 1);           \
                      fa2 = LD_A(c, 2*(q)+1, 0); fa3 = LD_A(c, 2*(q)+1, 1); }
#define LDB_ALL(c) { _Pragma("unroll") for (int n = 0; n < 4; ++n) {              \
                       bfr[n][0] = LD_B(c, n, 0); bfr[n][1] = LD_B(c, n, 1); } }
#define MFMA_Q(q) { __builtin_amdgcn_s_setprio(1);                                \
    _Pragma("unroll") for (int n = 0; n < 4; ++n) {                               \
      acc[2*(q)][n]   = __builtin_amdgcn_mfma_f32_16x16x32_fp8_fp8(bfr[n][0], fa0, acc[2*(q)][n],   0,0,0); \
      acc[2*(q)][n]   = __builtin_amdgcn_mfma_f32_16x16x32_fp8_fp8(bfr[n][1], fa1, acc[2*(q)][n],   0,0,0); \
      acc[2*(q)+1][n] = __builtin_amdgcn_mfma_f32_16x16x32_fp8_fp8(bfr[n][0], fa2, acc[2*(q)+1][n], 0,0,0); \
      acc[2*(q)+1][n] = __builtin_amdgcn_mfma_f32_16x16x32_fp8_fp8(bfr[n][1], fa3, acc[2*(q)+1][n], 0,0,0); } \
    __builtin_amdgcn_s_setprio(0); }

    // prologue: buf0.B(t0), buf0.A(t0), buf1.B(t1) -> 6 issues; first 4 = tile0
    STAGE_B(gB, 0, 0, 0); STAGE_B(gB, 0, 1, 0);
    STAGE_A(gA, 0, 0, 0); STAGE_A(gA, 0, 1, 0);
    STAGE_B(gB, 1, 0, 1); STAGE_B(gB, 1, 1, 1);
    VMC2();
    BAR();

    const unsigned char* gAt = gA;   // tile 2i base
    const unsigned char* gBt = gB;
    for (int i = 0; i < 4; ++i) {
        const bool s23 = (i < 3);

        LDA_Q(0, 0); LDB_ALL(0);
        STAGE_A(gAt, 1, 0, 1);
        BAR(); MFMA_Q(0); BAR();

        LDA_Q(0, 1);
        STAGE_A(gAt, 1, 1, 1);
        BAR(); MFMA_Q(1); BAR();

        LDA_Q(0, 2);
        if (s23) STAGE_B(gBt, 0, 0, 2);
        BAR(); MFMA_Q(2); BAR();

        LDA_Q(0, 3);
        if (s23) STAGE_B(gBt, 0, 1, 2);
        BAR(); MFMA_Q(3);
        if (s23) { VMC2(); } else { VMC0(); }
        BAR();

        LDA_Q(1, 0); LDB_ALL(1);
        if (s23) STAGE_A(gAt, 0, 0, 2);
        BAR(); MFMA_Q(0); BAR();

        LDA_Q(1, 1);
        if (s23) STAGE_A(gAt, 0, 1, 2);
        BAR(); MFMA_Q(1); BAR();

        LDA_Q(1, 2);
        if (s23) STAGE_B(gBt, 1, 0, 3);
        BAR(); MFMA_Q(2); BAR();

        LDA_Q(1, 3);
        if (s23) STAGE_B(gBt, 1, 1, 3);
        BAR(); MFMA_Q(3);
        if (s23) { VMC2(); }
        BAR();

        gAt += 128; gBt += 128;
    }

    // ---- epilogue: acc(+16*bias) -> swizzled fp8 LDS tile (256x256 = 64 KB) -> C ----
    {
        const int q  = lane >> 4;
        const int tr = wr * 128 + (lane & 15);
        #pragma unroll
        for (int n = 0; n < 4; ++n) {
            float4 bb = *(const float4*)(bias + n0 + wn * 64 + n * 16 + q * 4);
            const int g16 = wn * 4 + n;
            #pragma unroll
            for (int m = 0; m < 8; ++m) {
                const int trm = tr + m * 16;
                unsigned int pk = __builtin_amdgcn_cvt_pk_fp8_f32(
                    acc[m][n][0] + 16.f * bb.x, acc[m][n][1] + 16.f * bb.y, 0u, false);
                pk = __builtin_amdgcn_cvt_pk_fp8_f32(
                    acc[m][n][2] + 16.f * bb.z, acc[m][n][3] + 16.f * bb.w, pk, true);
                *(unsigned int*)(SH + trm * 256 + ((g16 ^ (trm & 15)) << 4) + q * 4) = pk;
            }
        }
        BAR();
        #pragma unroll
        for (int it = 0; it < 8; ++it) {
            const int f = it * 512 + tid;
            const int rr = f >> 4, gg = f & 15;
            uint4 v = *(const uint4*)(SH + rr * 256 + ((gg ^ (rr & 15)) << 4));
            *(uint4*)(C + (size_t)(row0 + rr) * 4096 + gg * 16 + n0) = v;
        }
    }
#undef STAGE_A
#undef STAGE_B
#undef LD_A
#undef LD_B
}

// ---------------- kernel 3: fp8-MFMA scores + softmax + pb-partials ------------------
__global__ __launch_bounds__(256) void mfscores(const unsigned char* __restrict__ Q,
                                                const unsigned char* __restrict__ K,
                                                float* __restrict__ P,
                                                float* __restrict__ pbpart)
{
    __shared__ float Pl[8 * 64];
    const int b = blockIdx.x, lc = blockIdx.y;       // (8, 64)
    const int tid = threadIdx.x, lane = tid & 63, w = tid >> 6;
    const int l0 = lc * 8;

    const int colr = lane & 15;
    const int ko   = lane >> 4;
    const int la   = l0 + w * 2 + (colr >> 3);
    const int hh   = colr & 7;
    const unsigned char* qrow = Q + (size_t)(b * 512 + la) * 4096 + hh * 512 + ko * 8;
    const unsigned char* krow = K + (size_t)(b * 512 + la) * 4096 + hh * 512 + ko * 8;

    f32x4 acc = (f32x4){0.f, 0.f, 0.f, 0.f};
    #pragma unroll
    for (int kt = 0; kt < 16; ++kt) {
        long long av = *(const long long*)(qrow + kt * 32);
        long long bv = *(const long long*)(krow + kt * 32);
        acc = __builtin_amdgcn_mfma_f32_16x16x32_fp8_fp8(av, bv, acc, 0, 0, 0);
    }

    const int lpr = ko >> 1;
    const int lpc = (lane >> 3) & 1;
    #pragma unroll
    for (int r = 0; r < 4; ++r) {
        float s = acc[r] * 1.7263349150062e-4f;   // 1/(256*sqrt(512)) -- Q',K' are x16
        float m = s;
        m = fmaxf(m, __shfl_xor(m, 1));
        m = fmaxf(m, __shfl_xor(m, 2));
        m = fmaxf(m, __shfl_xor(m, 4));
        float e = __expf(s - m);
        float ss = e;
        ss += __shfl_xor(ss, 1);
        ss += __shfl_xor(ss, 2);
        ss += __shfl_xor(ss, 4);
        float p = e / ss + 63.875f;               // fold uniform part
        if (lpr == lpc)
            Pl[(w * 2 + lpr) * 64 + ((ko & 1) * 4 + r) * 8 + (lane & 7)] = p;
    }
    __syncthreads();

    {
        const int l = tid >> 5, off = (tid & 31) * 2;
        float2 v = *(const float2*)&Pl[l * 64 + off];
        *(float2*)(P + (size_t)(b * 512 + l0 + l) * 64 + off) = v;
    }
    if (tid < 64) {
        float s = 0.f;
        #pragma unroll
        for (int l = 0; l < 8; ++l) s += Pl[l * 64 + tid];
        pbpart[((size_t)b * 64 + lc) * 64 + tid] = s;
    }
}

// ---------------- kernel 4: ypart[lc,b,hg,d] = sum_{l in chunk} P' * Xv --------------
__global__ __launch_bounds__(256) void ykern(const float* __restrict__ P,
                                             const float* __restrict__ Xv,
                                             float* __restrict__ ypart)
{
    __shared__ float Pl[128 * 64];
    __shared__ float Xl[128 * 64];
    const int b = blockIdx.x, dt = blockIdx.y, lc = blockIdx.z;
    const int tid = threadIdx.x;
    const int tm = tid & 15, te = tid >> 4;

    const float* Pg = P + ((size_t)b * 512 + lc * 128) * 64;
    #pragma unroll
    for (int i = 0; i < 8; ++i)
        *(float4*)&Pl[(i * 256 + tid) * 4] = *(const float4*)(Pg + (size_t)(i * 256 + tid) * 4);
    const float* Xg = Xv + ((size_t)b * 512 + lc * 128) * 512 + dt * 64;
    #pragma unroll
    for (int i = 0; i < 8; ++i) {
        int flat = i * 256 + tid;
        int r = flat >> 4, q = flat & 15;
        *(float4*)&Xl[r * 64 + q * 4] = *(const float4*)(Xg + (size_t)r * 512 + q * 4);
    }
    __syncthreads();

    float4 acc[4];
    #pragma unroll
    for (int i = 0; i < 4; ++i) acc[i] = make_float4(0.f, 0.f, 0.f, 0.f);

    for (int l = 0; l < 128; ++l) {
        float4 pv = *(const float4*)&Pl[l * 64 + tm * 4];
        float4 xv = *(const float4*)&Xl[l * 64 + te * 4];
        acc[0].x += pv.x * xv.x; acc[0].y += pv.x * xv.y; acc[0].z += pv.x * xv.z; acc[0].w += pv.x * xv.w;
        acc[1].x += pv.y * xv.x; acc[1].y += pv.y * xv.y; acc[1].z += pv.y * xv.z; acc[1].w += pv.y * xv.w;
        acc[2].x += pv.z * xv.x; acc[2].y += pv.z * xv.y; acc[2].z += pv.z * xv.z; acc[2].w += pv.z * xv.w;
        acc[3].x += pv.w * xv.x; acc[3].y += pv.w * xv.y; acc[3].z += pv.w * xv.z; acc[3].w += pv.w * xv.w;
    }
    #pragma unroll
    for (int i = 0; i < 4; ++i)
        *(float4*)&ypart[(((size_t)lc * 8 + b) * 64 + tm * 4 + i) * 512 + dt * 64 + te * 4] = acc[i];
}

// ---------------- kernel 5: split-K vgemm (yreduce fused into A-stage) ---------------
__global__ __launch_bounds__(256) void vgemm(const float* __restrict__ ypart,
                                             const float* __restrict__ Wv,
                                             float* __restrict__ partial)
{
    __shared__ float Al[64 * 64];
    __shared__ float Bl[64 * 64];
    const int et = blockIdx.x, kc = blockIdx.y;
    const int g = kc >> 3, d0 = (kc & 7) * 64, e0 = et * 64;
    const int tid = threadIdx.x;
    const int tm = tid & 15, te = tid >> 4;

    #pragma unroll
    for (int i = 0; i < 4; ++i) {
        int flat = i * 256 + tid;
        int bh = flat >> 4, dq = flat & 15;
        int yrow = (bh >> 3) * 64 + (bh & 7) * 8 + g;
        size_t base = ((size_t)(yrow >> 6) * 64 + (yrow & 63)) * 512 + d0 + dq * 4;
        float4 v = *(const float4*)(ypart + base);
        #pragma unroll
        for (int lc = 1; lc < 4; ++lc) {
            float4 t = *(const float4*)(ypart + (size_t)lc * 262144 + base);
            v.x += t.x; v.y += t.y; v.z += t.z; v.w += t.w;
        }
        *(float4*)&Al[bh * 64 + ((dq ^ (bh >> 2)) << 2)] = v;
    }
    #pragma unroll
    for (int i = 0; i < 4; ++i) {
        int flat = i * 256 + tid;
        int kk = flat >> 4, eq = flat & 15;
        *(float4*)&Bl[kk * 64 + eq * 4] =
            *(const float4*)(Wv + (size_t)(d0 + kk) * 4096 + g * 512 + e0 + eq * 4);
    }
    __syncthreads();

    float4 acc[4];
    #pragma unroll
    for (int j = 0; j < 4; ++j) acc[j] = make_float4(0.f, 0.f, 0.f, 0.f);

    for (int k = 0; k < 64; ++k) {
        float4 b4 = *(const float4*)&Bl[k * 64 + te * 4];
        const int gcol = (((k >> 2) ^ tm) << 2) + (k & 3);
        #pragma unroll
        for (int j = 0; j < 4; ++j) {
            float a = Al[(tm * 4 + j) * 64 + gcol];
            acc[j].x += a * b4.x; acc[j].y += a * b4.y;
            acc[j].z += a * b4.z; acc[j].w += a * b4.w;
        }
    }
    #pragma unroll
    for (int j = 0; j < 4; ++j)
        *(float4*)&partial[(size_t)kc * 32768 + (tm * 4 + j) * 512 + e0 + te * 4] = acc[j];
}

// ---------------- kernel 6: finalize: out = sum_kc partial + sum_g c*bv --------------
__global__ __launch_bounds__(256) void finalize(const float* __restrict__ partial,
                                                const float* __restrict__ pbpart,
                                                const float* __restrict__ bv,
                                                float* __restrict__ out)
{
    __shared__ float csh[8];
    const int blk = blockIdx.x;
    const int tid = threadIdx.x;
    const int b = blk >> 4, h = (blk >> 1) & 7;
    const int e = (blk & 1) * 256 + tid;

    if (tid < 8) {
        float s = 0.f;
        #pragma unroll 8
        for (int lcc = 0; lcc < 64; ++lcc)
            s += pbpart[((size_t)b * 64 + lcc) * 64 + h * 8 + tid];
        csh[tid] = s;
    }
    __syncthreads();

    const int i = ((b * 8 + h) << 9) + e;
    float s = 0.f;
    #pragma unroll
    for (int kc = 0; kc < 64; ++kc) s += partial[(size_t)kc * 32768 + i];
    float bt = 0.f;
    #pragma unroll
    for (int g = 0; g < 8; ++g) bt += csh[g] * bv[g * 512 + e];
    out[i] = s + bt;
}

extern "C" void kernel_launch(void* const* d_in, const int* in_sizes, int n_in,
                              void* d_out, int out_size, void* d_ws, size_t ws_size,
                              hipStream_t stream)
{
    const float* queries = (const float*)d_in[0];
    const float* keys    = (const float*)d_in[1];
    const float* values  = (const float*)d_in[2];
    const float* Wq      = (const float*)d_in[3];
    const float* bq      = (const float*)d_in[4];
    const float* Wk      = (const float*)d_in[5];
    const float* bk      = (const float*)d_in[6];
    const float* Wv      = (const float*)d_in[7];
    const float* bv      = (const float*)d_in[8];

    unsigned char* xq  = (unsigned char*)d_ws;          // 2 MB each
    unsigned char* xk  = xq  + (1u << 21);
    unsigned char* wtq = xk  + (1u << 21);
    unsigned char* wtk = wtq + (1u << 21);
    unsigned char* Q   = wtk + (1u << 21);              // 16 MB each
    unsigned char* Kb  = Q   + (1u << 24);
    float* P      = (float*)(Kb + (1u << 24));
    float* pbpart = P + 262144;
    float* ypart  = pbpart + 32768;
    float* part   = ypart + 4 * 262144;

    prep<<<dim3(2048, 1, 4), 256, 0, stream>>>(queries, keys, xq, xk, Wq, Wk, wtq, wtk);
    gemm_bt256<<<dim3(16, 16, 2), 512, 0, stream>>>(xq, xk, wtq, wtk, bq, bk, Q, Kb);
    mfscores<<<dim3(8, 64), 256, 0, stream>>>(Q, Kb, P, pbpart);
    ykern<<<dim3(8, 8, 4), 256, 0, stream>>>(P, values, ypart);
    vgemm<<<dim3(8, 64), 256, 0, stream>>>(ypart, Wv, part);
    finalize<<<dim3(128), 256, 0, stream>>>(part, pbpart, bv, (float*)d_out);
}

// Round 10
// 81.653 us; speedup vs baseline: 2.3984x; 1.0870x over previous
//
#include <hip/hip_runtime.h>

// B=8, L=512, D=512, H=8. Q/K GEMMs: M=4096, N=4096, K=512 -- fp8-e4m3 MFMA.
// R10: LDS rows = 128B (BK=128 fp8) with 8-granule XOR swizzle (the R7-proven bank
// pattern). R9's 64B rows / 4-granule swizzle caused 4-way ds_read_b64 conflicts
// (9.7M SQ_LDS_BANK_CONFLICT). LDS 128KB, 2 outer iters x 8 phases, VMC4.
// V path (all f32): P' = softmax + 63.875; Y = sum_l P'*Xv; out = Y @ Wv + c*bv.

using f32x4 = __attribute__((ext_vector_type(4))) float;

__device__ __forceinline__ float bflo(unsigned int u) {
    union { unsigned int u; float f; } c; c.u = u << 16; return c.f;
}

#define GLOAD16(gp, lp) __builtin_amdgcn_global_load_lds( \
    (const __attribute__((address_space(1))) unsigned int*)(gp), \
    (__attribute__((address_space(3))) unsigned int*)(lp), 16, 0, 0)

// ---------------- kernel 1: prep = convert Xq/Xk -> fp8 (z=0,1); transpose W*16 -> fp8 (z=2,3)
__global__ __launch_bounds__(256) void prep(
    const float* __restrict__ x0, const float* __restrict__ x1,
    unsigned char* __restrict__ o0, unsigned char* __restrict__ o1,
    const float* __restrict__ w0, const float* __restrict__ w1,
    unsigned char* __restrict__ t0, unsigned char* __restrict__ t1)
{
    const int z = blockIdx.z;
    if (z < 2) {
        const float* src = (z == 0) ? x0 : x1;
        unsigned char* dst = (z == 0) ? o0 : o1;
        int i = (blockIdx.x * 256 + threadIdx.x) * 8;
        if (i < 2097152) {
            float4 a = *(const float4*)(src + i);
            float4 b = *(const float4*)(src + i + 4);
            uint2 u;
            u.x = __builtin_amdgcn_cvt_pk_fp8_f32(a.x, a.y, 0u, false);
            u.x = __builtin_amdgcn_cvt_pk_fp8_f32(a.z, a.w, u.x, true);
            u.y = __builtin_amdgcn_cvt_pk_fp8_f32(b.x, b.y, 0u, false);
            u.y = __builtin_amdgcn_cvt_pk_fp8_f32(b.z, b.w, u.y, true);
            *(uint2*)(dst + i) = u;
        }
    } else {
        const float* W = (z == 2) ? w0 : w1;
        unsigned char* T = (z == 2) ? t0 : t1;
        __shared__ float tile[32][33];
        const int n0 = (blockIdx.x & 127) * 32, k0 = (blockIdx.x >> 7) * 32;
        const int tx = threadIdx.x & 31, ty = threadIdx.x >> 5;   // (32, 8)
        #pragma unroll
        for (int j = 0; j < 32; j += 8)
            tile[ty + j][tx] = W[(size_t)(k0 + ty + j) * 4096 + n0 + tx];
        __syncthreads();
        // thread -> (n = ty*4 + tx>>3, kq = tx&7): one u32 of 4 fp8 (W x16)
        const int n = ty * 4 + (tx >> 3), kq = tx & 7;
        unsigned int pk = __builtin_amdgcn_cvt_pk_fp8_f32(
            16.f * tile[kq * 4 + 0][n], 16.f * tile[kq * 4 + 1][n], 0u, false);
        pk = __builtin_amdgcn_cvt_pk_fp8_f32(
            16.f * tile[kq * 4 + 2][n], 16.f * tile[kq * 4 + 3][n], pk, true);
        *(unsigned int*)(T + (size_t)(n0 + n) * 512 + k0 + kq * 4) = pk;
    }
}

// ---------------- kernel 2: 256^2 FP8 GEMM, 128B-row swizzled LDS, fp8 epilogue ------
__global__ __launch_bounds__(512) void gemm_bt256(
    const unsigned char* __restrict__ a0, const unsigned char* __restrict__ a1,
    const unsigned char* __restrict__ w0, const unsigned char* __restrict__ w1,
    const float* __restrict__ b0, const float* __restrict__ b1,
    unsigned char* __restrict__ c0, unsigned char* __restrict__ c1)
{
    const unsigned char* A;  const unsigned char* Bt; const float* bias; unsigned char* C;
    if (blockIdx.z == 0) { A = a0; Bt = w0; bias = b0; C = c0; }
    else                 { A = a1; Bt = w1; bias = b1; C = c1; }

    __shared__ __align__(16) unsigned char SH[131072];   // A: 2x32K @0 | B: 2x32K @65536

    const int tid  = threadIdx.x;
    const int lane = tid & 63;
    const int wid  = tid >> 6;
    const int wr   = wid >> 2;
    const int wn   = wid & 3;
    const int linb = blockIdx.y * 16 + blockIdx.x;
    const int swz  = (linb & 7) * 32 + (linb >> 3);
    const int bx   = (swz >> 6) * 4 + (swz & 3);
    const int by   = (swz >> 2) & 15;
    const int row0 = by * 256;
    const int n0   = bx * 256;

    // staging: row = 128B (one K-mega-tile of 128 fp8); GLOAD16 = 8 rows;
    // lane -> row lane>>3, granule (lane&7)^(lane>>3) (inverse of read swizzle)
    const int sgran = (lane & 7) ^ (lane >> 3);
    const unsigned char* gA = A  + (size_t)(row0 + wid * 8 + (lane >> 3)) * 512 + sgran * 16;
    const unsigned char* gB = Bt + (size_t)(n0   + wid * 8 + (lane >> 3)) * 512 + sgran * 16;

#define STAGE_A(gp, buf, half, trel)                                              \
    { GLOAD16((gp) + ((half) * 128     ) * 512 + (trel) * 128,                    \
              SH + (buf) * 32768 + (((half) * 128      + wid * 8)) * 128);        \
      GLOAD16((gp) + ((half) * 128 + 64) * 512 + (trel) * 128,                    \
              SH + (buf) * 32768 + (((half) * 128 + 64 + wid * 8)) * 128); }
#define STAGE_B(gp, buf, half, trel)                                              \
    { GLOAD16((gp) + ((half) * 128     ) * 512 + (trel) * 128,                    \
              SH + 65536 + (buf) * 32768 + (((half) * 128      + wid * 8)) * 128);\
      GLOAD16((gp) + ((half) * 128 + 64) * 512 + (trel) * 128,                    \
              SH + 65536 + (buf) * 32768 + (((half) * 128 + 64 + wid * 8)) * 128); }

    // fragment reads: row r (r&7 == lane&7), k-bytes s*32 + ko*8 (ko = lane>>4);
    // granule gg = s*2 | (ko>>1); swizzled g = gg ^ (r&7); byte = g*16 + (ko&1)*8
    const int koh = lane >> 5, kol = (lane >> 4) & 1, l7 = lane & 7;
    const char* bA0 = (const char*)SH + (wr * 128 + (lane & 15)) * 128 + (((0 | koh) ^ l7) << 4) + kol * 8;
    const char* bA1 = (const char*)SH + (wr * 128 + (lane & 15)) * 128 + (((2 | koh) ^ l7) << 4) + kol * 8;
    const char* bA2 = (const char*)SH + (wr * 128 + (lane & 15)) * 128 + (((4 | koh) ^ l7) << 4) + kol * 8;
    const char* bA3 = (const char*)SH + (wr * 128 + (lane & 15)) * 128 + (((6 | koh) ^ l7) << 4) + kol * 8;
    const char* bB0 = (const char*)SH + 65536 + (wn * 64 + (lane & 15)) * 128 + (((0 | koh) ^ l7) << 4) + kol * 8;
    const char* bB1 = (const char*)SH + 65536 + (wn * 64 + (lane & 15)) * 128 + (((2 | koh) ^ l7) << 4) + kol * 8;
    const char* bB2 = (const char*)SH + 65536 + (wn * 64 + (lane & 15)) * 128 + (((4 | koh) ^ l7) << 4) + kol * 8;
    const char* bB3 = (const char*)SH + 65536 + (wn * 64 + (lane & 15)) * 128 + (((6 | koh) ^ l7) << 4) + kol * 8;

#define BAp(s) ((s) == 0 ? bA0 : (s) == 1 ? bA1 : (s) == 2 ? bA2 : bA3)
#define BBp(s) ((s) == 0 ? bB0 : (s) == 1 ? bB1 : (s) == 2 ? bB2 : bB3)
#define LD_A(c, m, s) (*(const long long*)(BAp(s) + (c) * 32768 + (m) * 2048))
#define LD_B(c, n, s) (*(const long long*)(BBp(s) + (c) * 32768 + (n) * 2048))

#define BAR() __builtin_amdgcn_s_barrier()
#define VMC4() asm volatile("s_waitcnt vmcnt(4)" ::: "memory")
#define VMC0() asm volatile("s_waitcnt vmcnt(0)" ::: "memory")

    f32x4 acc[8][4];
    #pragma unroll
    for (int m = 0; m < 8; ++m)
        #pragma unroll
        for (int n = 0; n < 4; ++n)
            acc[m][n] = (f32x4){0.f, 0.f, 0.f, 0.f};

    long long bfr[4][4];
    long long fa0, fa1, fa2, fa3, fa4, fa5, fa6, fa7;

#define LDA_Q(c, q) { fa0 = LD_A(c, 2*(q), 0);   fa1 = LD_A(c, 2*(q), 1);         \
                      fa2 = LD_A(c, 2*(q), 2);   fa3 = LD_A(c, 2*(q), 3);         \
                      fa4 = LD_A(c, 2*(q)+1, 0); fa5 = LD_A(c, 2*(q)+1, 1);       \
                      fa6 = LD_A(c, 2*(q)+1, 2); fa7 = LD_A(c, 2*(q)+1, 3); }
#define LDB_ALL(c) { _Pragma("unroll") for (int n = 0; n < 4; ++n) {              \
                       bfr[n][0] = LD_B(c, n, 0); bfr[n][1] = LD_B(c, n, 1);      \
                       bfr[n][2] = LD_B(c, n, 2); bfr[n][3] = LD_B(c, n, 3); } }
#define MFMA_Q(q) { __builtin_amdgcn_s_setprio(1);                                \
    _Pragma("unroll") for (int n = 0; n < 4; ++n) {                               \
      acc[2*(q)][n]   = __builtin_amdgcn_mfma_f32_16x16x32_fp8_fp8(bfr[n][0], fa0, acc[2*(q)][n],   0,0,0); \
      acc[2*(q)][n]   = __builtin_amdgcn_mfma_f32_16x16x32_fp8_fp8(bfr[n][1], fa1, acc[2*(q)][n],   0,0,0); \
      acc[2*(q)][n]   = __builtin_amdgcn_mfma_f32_16x16x32_fp8_fp8(bfr[n][2], fa2, acc[2*(q)][n],   0,0,0); \
      acc[2*(q)][n]   = __builtin_amdgcn_mfma_f32_16x16x32_fp8_fp8(bfr[n][3], fa3, acc[2*(q)][n],   0,0,0); \
      acc[2*(q)+1][n] = __builtin_amdgcn_mfma_f32_16x16x32_fp8_fp8(bfr[n][0], fa4, acc[2*(q)+1][n], 0,0,0); \
      acc[2*(q)+1][n] = __builtin_amdgcn_mfma_f32_16x16x32_fp8_fp8(bfr[n][1], fa5, acc[2*(q)+1][n], 0,0,0); \
      acc[2*(q)+1][n] = __builtin_amdgcn_mfma_f32_16x16x32_fp8_fp8(bfr[n][2], fa6, acc[2*(q)+1][n], 0,0,0); \
      acc[2*(q)+1][n] = __builtin_amdgcn_mfma_f32_16x16x32_fp8_fp8(bfr[n][3], fa7, acc[2*(q)+1][n], 0,0,0); } \
    __builtin_amdgcn_s_setprio(0); }

    // prologue: B(t0) 4, A(t0) 4, B(t1) 4 issues; VMC4 -> tile0 resident
    STAGE_B(gB, 0, 0, 0); STAGE_B(gB, 0, 1, 0);
    STAGE_A(gA, 0, 0, 0); STAGE_A(gA, 0, 1, 0);
    STAGE_B(gB, 1, 0, 1); STAGE_B(gB, 1, 1, 1);
    VMC4();
    BAR();

    const unsigned char* gAt = gA;   // k-base of tile 2i
    const unsigned char* gBt = gB;
    for (int i = 0; i < 2; ++i) {
        const bool s23 = (i < 1);

        LDA_Q(0, 0); LDB_ALL(0);
        STAGE_A(gAt, 1, 0, 1);
        BAR(); MFMA_Q(0); BAR();

        LDA_Q(0, 1);
        STAGE_A(gAt, 1, 1, 1);
        BAR(); MFMA_Q(1); BAR();

        LDA_Q(0, 2);
        if (s23) STAGE_B(gBt, 0, 0, 2);
        BAR(); MFMA_Q(2); BAR();

        LDA_Q(0, 3);
        if (s23) STAGE_B(gBt, 0, 1, 2);
        BAR(); MFMA_Q(3);
        if (s23) { VMC4(); } else { VMC0(); }
        BAR();

        LDA_Q(1, 0); LDB_ALL(1);
        if (s23) STAGE_A(gAt, 0, 0, 2);
        BAR(); MFMA_Q(0); BAR();

        LDA_Q(1, 1);
        if (s23) STAGE_A(gAt, 0, 1, 2);
        BAR(); MFMA_Q(1); BAR();

        LDA_Q(1, 2);
        if (s23) STAGE_B(gBt, 1, 0, 3);
        BAR(); MFMA_Q(2); BAR();

        LDA_Q(1, 3);
        if (s23) STAGE_B(gBt, 1, 1, 3);
        BAR(); MFMA_Q(3);
        if (s23) { VMC4(); }
        BAR();

        gAt += 256; gBt += 256;
    }

    // ---- epilogue: acc(+16*bias) -> swizzled fp8 LDS tile (256x256 = 64 KB) -> C ----
    {
        const int q  = lane >> 4;
        const int tr = wr * 128 + (lane & 15);
        #pragma unroll
        for (int n = 0; n < 4; ++n) {
            float4 bb = *(const float4*)(bias + n0 + wn * 64 + n * 16 + q * 4);
            const int g16 = wn * 4 + n;
            #pragma unroll
            for (int m = 0; m < 8; ++m) {
                const int trm = tr + m * 16;
                unsigned int pk = __builtin_amdgcn_cvt_pk_fp8_f32(
                    acc[m][n][0] + 16.f * bb.x, acc[m][n][1] + 16.f * bb.y, 0u, false);
                pk = __builtin_amdgcn_cvt_pk_fp8_f32(
                    acc[m][n][2] + 16.f * bb.z, acc[m][n][3] + 16.f * bb.w, pk, true);
                *(unsigned int*)(SH + trm * 256 + ((g16 ^ (trm & 15)) << 4) + q * 4) = pk;
            }
        }
        BAR();
        #pragma unroll
        for (int it = 0; it < 8; ++it) {
            const int f = it * 512 + tid;
            const int rr = f >> 4, gg = f & 15;
            uint4 v = *(const uint4*)(SH + rr * 256 + ((gg ^ (rr & 15)) << 4));
            *(uint4*)(C + (size_t)(row0 + rr) * 4096 + gg * 16 + n0) = v;
        }
    }
#undef STAGE_A
#undef STAGE_B
#undef LD_A
#undef LD_B
#undef BAp
#undef BBp
}

// ---------------- kernel 3: fp8-MFMA scores + softmax + pb-partials ------------------
__global__ __launch_bounds__(256) void mfscores(const unsigned char* __restrict__ Q,
                                                const unsigned char* __restrict__ K,
                                                float* __restrict__ P,
                                                float* __restrict__ pbpart)
{
    __shared__ float Pl[8 * 64];
    const int b = blockIdx.x, lc = blockIdx.y;       // (8, 64)
    const int tid = threadIdx.x, lane = tid & 63, w = tid >> 6;
    const int l0 = lc * 8;

    const int colr = lane & 15;
    const int ko   = lane >> 4;
    const int la   = l0 + w * 2 + (colr >> 3);
    const int hh   = colr & 7;
    const unsigned char* qrow = Q + (size_t)(b * 512 + la) * 4096 + hh * 512 + ko * 8;
    const unsigned char* krow = K + (size_t)(b * 512 + la) * 4096 + hh * 512 + ko * 8;

    f32x4 acc = (f32x4){0.f, 0.f, 0.f, 0.f};
    #pragma unroll
    for (int kt = 0; kt < 16; ++kt) {
        long long av = *(const long long*)(qrow + kt * 32);
        long long bv = *(const long long*)(krow + kt * 32);
        acc = __builtin_amdgcn_mfma_f32_16x16x32_fp8_fp8(av, bv, acc, 0, 0, 0);
    }

    const int lpr = ko >> 1;
    const int lpc = (lane >> 3) & 1;
    #pragma unroll
    for (int r = 0; r < 4; ++r) {
        float s = acc[r] * 1.7263349150062e-4f;   // 1/(256*sqrt(512)) -- Q',K' are x16
        float m = s;
        m = fmaxf(m, __shfl_xor(m, 1));
        m = fmaxf(m, __shfl_xor(m, 2));
        m = fmaxf(m, __shfl_xor(m, 4));
        float e = __expf(s - m);
        float ss = e;
        ss += __shfl_xor(ss, 1);
        ss += __shfl_xor(ss, 2);
        ss += __shfl_xor(ss, 4);
        float p = e / ss + 63.875f;               // fold uniform part
        if (lpr == lpc)
            Pl[(w * 2 + lpr) * 64 + ((ko & 1) * 4 + r) * 8 + (lane & 7)] = p;
    }
    __syncthreads();

    {
        const int l = tid >> 5, off = (tid & 31) * 2;
        float2 v = *(const float2*)&Pl[l * 64 + off];
        *(float2*)(P + (size_t)(b * 512 + l0 + l) * 64 + off) = v;
    }
    if (tid < 64) {
        float s = 0.f;
        #pragma unroll
        for (int l = 0; l < 8; ++l) s += Pl[l * 64 + tid];
        pbpart[((size_t)b * 64 + lc) * 64 + tid] = s;
    }
}

// ---------------- kernel 4: ypart[lc,b,hg,d] = sum_{l in chunk} P' * Xv --------------
__global__ __launch_bounds__(256) void ykern(const float* __restrict__ P,
                                             const float* __restrict__ Xv,
                                             float* __restrict__ ypart)
{
    __shared__ float Pl[128 * 64];
    __shared__ float Xl[128 * 64];
    const int b = blockIdx.x, dt = blockIdx.y, lc = blockIdx.z;
    const int tid = threadIdx.x;
    const int tm = tid & 15, te = tid >> 4;

    const float* Pg = P + ((size_t)b * 512 + lc * 128) * 64;
    #pragma unroll
    for (int i = 0; i < 8; ++i)
        *(float4*)&Pl[(i * 256 + tid) * 4] = *(const float4*)(Pg + (size_t)(i * 256 + tid) * 4);
    const float* Xg = Xv + ((size_t)b * 512 + lc * 128) * 512 + dt * 64;
    #pragma unroll
    for (int i = 0; i < 8; ++i) {
        int flat = i * 256 + tid;
        int r = flat >> 4, q = flat & 15;
        *(float4*)&Xl[r * 64 + q * 4] = *(const float4*)(Xg + (size_t)r * 512 + q * 4);
    }
    __syncthreads();

    float4 acc[4];
    #pragma unroll
    for (int i = 0; i < 4; ++i) acc[i] = make_float4(0.f, 0.f, 0.f, 0.f);

    for (int l = 0; l < 128; ++l) {
        float4 pv = *(const float4*)&Pl[l * 64 + tm * 4];
        float4 xv = *(const float4*)&Xl[l * 64 + te * 4];
        acc[0].x += pv.x * xv.x; acc[0].y += pv.x * xv.y; acc[0].z += pv.x * xv.z; acc[0].w += pv.x * xv.w;
        acc[1].x += pv.y * xv.x; acc[1].y += pv.y * xv.y; acc[1].z += pv.y * xv.z; acc[1].w += pv.y * xv.w;
        acc[2].x += pv.z * xv.x; acc[2].y += pv.z * xv.y; acc[2].z += pv.z * xv.z; acc[2].w += pv.z * xv.w;
        acc[3].x += pv.w * xv.x; acc[3].y += pv.w * xv.y; acc[3].z += pv.w * xv.z; acc[3].w += pv.w * xv.w;
    }
    #pragma unroll
    for (int i = 0; i < 4; ++i)
        *(float4*)&ypart[(((size_t)lc * 8 + b) * 64 + tm * 4 + i) * 512 + dt * 64 + te * 4] = acc[i];
}

// ---------------- kernel 5: split-K vgemm (yreduce fused into A-stage) ---------------
__global__ __launch_bounds__(256) void vgemm(const float* __restrict__ ypart,
                                             const float* __restrict__ Wv,
                                             float* __restrict__ partial)
{
    __shared__ float Al[64 * 64];
    __shared__ float Bl[64 * 64];
    const int et = blockIdx.x, kc = blockIdx.y;
    const int g = kc >> 3, d0 = (kc & 7) * 64, e0 = et * 64;
    const int tid = threadIdx.x;
    const int tm = tid & 15, te = tid >> 4;

    #pragma unroll
    for (int i = 0; i < 4; ++i) {
        int flat = i * 256 + tid;
        int bh = flat >> 4, dq = flat & 15;
        int yrow = (bh >> 3) * 64 + (bh & 7) * 8 + g;
        size_t base = ((size_t)(yrow >> 6) * 64 + (yrow & 63)) * 512 + d0 + dq * 4;
        float4 v = *(const float4*)(ypart + base);
        #pragma unroll
        for (int lc = 1; lc < 4; ++lc) {
            float4 t = *(const float4*)(ypart + (size_t)lc * 262144 + base);
            v.x += t.x; v.y += t.y; v.z += t.z; v.w += t.w;
        }
        *(float4*)&Al[bh * 64 + ((dq ^ (bh >> 2)) << 2)] = v;
    }
    #pragma unroll
    for (int i = 0; i < 4; ++i) {
        int flat = i * 256 + tid;
        int kk = flat >> 4, eq = flat & 15;
        *(float4*)&Bl[kk * 64 + eq * 4] =
            *(const float4*)(Wv + (size_t)(d0 + kk) * 4096 + g * 512 + e0 + eq * 4);
    }
    __syncthreads();

    float4 acc[4];
    #pragma unroll
    for (int j = 0; j < 4; ++j) acc[j] = make_float4(0.f, 0.f, 0.f, 0.f);

    for (int k = 0; k < 64; ++k) {
        float4 b4 = *(const float4*)&Bl[k * 64 + te * 4];
        const int gcol = (((k >> 2) ^ tm) << 2) + (k & 3);
        #pragma unroll
        for (int j = 0; j < 4; ++j) {
            float a = Al[(tm * 4 + j) * 64 + gcol];
            acc[j].x += a * b4.x; acc[j].y += a * b4.y;
            acc[j].z += a * b4.z; acc[j].w += a * b4.w;
        }
    }
    #pragma unroll
    for (int j = 0; j < 4; ++j)
        *(float4*)&partial[(size_t)kc * 32768 + (tm * 4 + j) * 512 + e0 + te * 4] = acc[j];
}

// ---------------- kernel 6: finalize: out = sum_kc partial + sum_g c*bv --------------
__global__ __launch_bounds__(256) void finalize(const float* __restrict__ partial,
                                                const float* __restrict__ pbpart,
                                                const float* __restrict__ bv,
                                                float* __restrict__ out)
{
    __shared__ float csh[8];
    const int blk = blockIdx.x;
    const int tid = threadIdx.x;
    const int b = blk >> 4, h = (blk >> 1) & 7;
    const int e = (blk & 1) * 256 + tid;

    if (tid < 8) {
        float s = 0.f;
        #pragma unroll 8
        for (int lcc = 0; lcc < 64; ++lcc)
            s += pbpart[((size_t)b * 64 + lcc) * 64 + h * 8 + tid];
        csh[tid] = s;
    }
    __syncthreads();

    const int i = ((b * 8 + h) << 9) + e;
    float s = 0.f;
    #pragma unroll
    for (int kc = 0; kc < 64; ++kc) s += partial[(size_t)kc * 32768 + i];
    float bt = 0.f;
    #pragma unroll
    for (int g = 0; g < 8; ++g) bt += csh[g] * bv[g * 512 + e];
    out[i] = s + bt;
}

extern "C" void kernel_launch(void* const* d_in, const int* in_sizes, int n_in,
                              void* d_out, int out_size, void* d_ws, size_t ws_size,
                              hipStream_t stream)
{
    const float* queries = (const float*)d_in[0];
    const float* keys    = (const float*)d_in[1];
    const float* values  = (const float*)d_in[2];
    const float* Wq      = (const float*)d_in[3];
    const float* bq      = (const float*)d_in[4];
    const float* Wk      = (const float*)d_in[5];
    const float* bk      = (const float*)d_in[6];
    const float* Wv      = (const float*)d_in[7];
    const float* bv      = (const float*)d_in[8];

    unsigned char* xq  = (unsigned char*)d_ws;          // 2 MB each
    unsigned char* xk  = xq  + (1u << 21);
    unsigned char* wtq = xk  + (1u << 21);
    unsigned char* wtk = wtq + (1u << 21);
    unsigned char* Q   = wtk + (1u << 21);              // 16 MB each
    unsigned char* Kb  = Q   + (1u << 24);
    float* P      = (float*)(Kb + (1u << 24));
    float* pbpart = P + 262144;
    float* ypart  = pbpart + 32768;
    float* part   = ypart + 4 * 262144;

    prep<<<dim3(2048, 1, 4), 256, 0, stream>>>(queries, keys, xq, xk, Wq, Wk, wtq, wtk);
    gemm_bt256<<<dim3(16, 16, 2), 512, 0, stream>>>(xq, xk, wtq, wtk, bq, bk, Q, Kb);
    mfscores<<<dim3(8, 64), 256, 0, stream>>>(Q, Kb, P, pbpart);
    ykern<<<dim3(8, 8, 4), 256, 0, stream>>>(P, values, ypart);
    vgemm<<<dim3(8, 64), 256, 0, stream>>>(ypart, Wv, part);
    finalize<<<dim3(128), 256, 0, stream>>>(part, pbpart, bv, (float*)d_out);
}

// Round 11
// 81.020 us; speedup vs baseline: 2.4171x; 1.0078x over previous
//
#include <hip/hip_runtime.h>

// B=8, L=512, D=512, H=8. Q/K GEMMs: M=4096, N=4096, K=512 -- fp8-e4m3 MFMA.
// R11: 64KB-LDS fp8 gemm. Row-pair packing: LDS row j (128B) holds logical rows j
// (granules 0-3) and j+128 (granules 4-7) of a 64B K-tile, XOR g^=(j&7).
// -> 2 blocks/CU (vs R10's 128KB/1 block) with the R7-proven 2-way bank pattern.
// Staging: linear LDS dest, inverse-permuted per-lane global source. vmcnt(2).
// V path (all f32): P' = softmax + 63.875; Y = sum_l P'*Xv; out = Y @ Wv + c*bv.

using f32x4 = __attribute__((ext_vector_type(4))) float;

__device__ __forceinline__ float bflo(unsigned int u) {
    union { unsigned int u; float f; } c; c.u = u << 16; return c.f;
}

#define GLOAD16(gp, lp) __builtin_amdgcn_global_load_lds( \
    (const __attribute__((address_space(1))) unsigned int*)(gp), \
    (__attribute__((address_space(3))) unsigned int*)(lp), 16, 0, 0)

// ---------------- kernel 1: prep = convert Xq/Xk -> fp8 (z=0,1); transpose W*16 -> fp8 (z=2,3)
__global__ __launch_bounds__(256) void prep(
    const float* __restrict__ x0, const float* __restrict__ x1,
    unsigned char* __restrict__ o0, unsigned char* __restrict__ o1,
    const float* __restrict__ w0, const float* __restrict__ w1,
    unsigned char* __restrict__ t0, unsigned char* __restrict__ t1)
{
    const int z = blockIdx.z;
    if (z < 2) {
        const float* src = (z == 0) ? x0 : x1;
        unsigned char* dst = (z == 0) ? o0 : o1;
        int i = (blockIdx.x * 256 + threadIdx.x) * 8;
        if (i < 2097152) {
            float4 a = *(const float4*)(src + i);
            float4 b = *(const float4*)(src + i + 4);
            uint2 u;
            u.x = __builtin_amdgcn_cvt_pk_fp8_f32(a.x, a.y, 0u, false);
            u.x = __builtin_amdgcn_cvt_pk_fp8_f32(a.z, a.w, u.x, true);
            u.y = __builtin_amdgcn_cvt_pk_fp8_f32(b.x, b.y, 0u, false);
            u.y = __builtin_amdgcn_cvt_pk_fp8_f32(b.z, b.w, u.y, true);
            *(uint2*)(dst + i) = u;
        }
    } else {
        const float* W = (z == 2) ? w0 : w1;
        unsigned char* T = (z == 2) ? t0 : t1;
        __shared__ float tile[32][33];
        const int n0 = (blockIdx.x & 127) * 32, k0 = (blockIdx.x >> 7) * 32;
        const int tx = threadIdx.x & 31, ty = threadIdx.x >> 5;   // (32, 8)
        #pragma unroll
        for (int j = 0; j < 32; j += 8)
            tile[ty + j][tx] = W[(size_t)(k0 + ty + j) * 4096 + n0 + tx];
        __syncthreads();
        const int n = ty * 4 + (tx >> 3), kq = tx & 7;
        unsigned int pk = __builtin_amdgcn_cvt_pk_fp8_f32(
            16.f * tile[kq * 4 + 0][n], 16.f * tile[kq * 4 + 1][n], 0u, false);
        pk = __builtin_amdgcn_cvt_pk_fp8_f32(
            16.f * tile[kq * 4 + 2][n], 16.f * tile[kq * 4 + 3][n], pk, true);
        *(unsigned int*)(T + (size_t)(n0 + n) * 512 + k0 + kq * 4) = pk;
    }
}

// ---------------- kernel 2: 256^2 FP8 GEMM, 64KB row-pair-packed LDS -----------------
__global__ __launch_bounds__(512) void gemm_bt256(
    const unsigned char* __restrict__ a0, const unsigned char* __restrict__ a1,
    const unsigned char* __restrict__ w0, const unsigned char* __restrict__ w1,
    const float* __restrict__ b0, const float* __restrict__ b1,
    unsigned char* __restrict__ c0, unsigned char* __restrict__ c1)
{
    const unsigned char* A;  const unsigned char* Bt; const float* bias; unsigned char* C;
    if (blockIdx.z == 0) { A = a0; Bt = w0; bias = b0; C = c0; }
    else                 { A = a1; Bt = w1; bias = b1; C = c1; }

    __shared__ __align__(16) unsigned char SH[65536];   // A: buf0@0 buf1@16384 | B: buf0@32768 buf1@49152

    const int tid  = threadIdx.x;
    const int lane = tid & 63;
    const int wid  = tid >> 6;
    const int wr   = wid >> 2;
    const int wn   = wid & 3;
    const int linb = blockIdx.y * 16 + blockIdx.x;
    const int swz  = (linb & 7) * 32 + (linb >> 3);
    const int bx   = (swz >> 6) * 4 + (swz & 3);
    const int by   = (swz >> 2) & 15;
    const int row0 = by * 256;
    const int n0   = bx * 256;

    // ---- staging geometry (per-thread, tile-invariant) ----
    // chunk c covers LDS rows c*64..c*64+63; thread S=tid -> LDS row c*64+(S>>3), granule S&7.
    // logical granule lg = (S&7)^((S>>3)&7); hi = lg>>2 selects row+128; lo = lg&3 k-16B.
    const int lgs = (tid & 7) ^ ((tid >> 3) & 7);
    const int shi = lgs >> 2, slo = lgs & 3;
    const int srow0 = (tid >> 3) + shi * 128;            // chunk 0 logical row; chunk1 = +64
    const unsigned char* gA = A  + (size_t)(row0 + srow0) * 512 + slo * 16;
    const unsigned char* gB = Bt + (size_t)(n0   + srow0) * 512 + slo * 16;

    // STAGE one chunk (8KB): global = gp + c*64rows + trel*64 k-bytes; LDS = linear.
#define STAGE_A(gp, buf, c, trel)                                                 \
    GLOAD16((gp) + (c) * (64 * 512) + (trel) * 64,                                \
            SH + (buf) * 16384 + (c) * 8192 + wid * 1024)
#define STAGE_B(gp, buf, c, trel)                                                 \
    GLOAD16((gp) + (c) * (64 * 512) + (trel) * 64,                                \
            SH + 32768 + (buf) * 16384 + (c) * 8192 + wid * 1024)

    // ---- fragment read bases ----
    // logical row r, k-byte s*32+ko*8 (ko=lane>>4): LDS row j=r&127, lg=s*2+(ko>>1)+(r>>7)*4,
    // g = lg ^ (j&7); j&7 == lane&7 for all fragment rows.
    const int l7 = lane & 7, koh = lane >> 5, kol = (lane >> 4) & 1, l15 = lane & 15;
    const char* bA0 = (const char*)SH + l15 * 128 + (((0 * 2 + koh + wr * 4) ^ l7) << 4) + kol * 8;
    const char* bA1 = (const char*)SH + l15 * 128 + (((1 * 2 + koh + wr * 4) ^ l7) << 4) + kol * 8;
    const char* bB0 = (const char*)SH + 32768 + (wn & 1) * 8192 + l15 * 128
                      + (((0 * 2 + koh + (wn >> 1) * 4) ^ l7) << 4) + kol * 8;
    const char* bB1 = (const char*)SH + 32768 + (wn & 1) * 8192 + l15 * 128
                      + (((1 * 2 + koh + (wn >> 1) * 4) ^ l7) << 4) + kol * 8;

#define LD_A(c, m, s) (*(const long long*)(((s) ? bA1 : bA0) + (c) * 16384 + (m) * 2048))
#define LD_B(c, n, s) (*(const long long*)(((s) ? bB1 : bB0) + (c) * 16384 + (n) * 2048))

#define BAR() __builtin_amdgcn_s_barrier()
#define VMC2() asm volatile("s_waitcnt vmcnt(2)" ::: "memory")
#define VMC0() asm volatile("s_waitcnt vmcnt(0)" ::: "memory")

    f32x4 acc[8][4];
    #pragma unroll
    for (int m = 0; m < 8; ++m)
        #pragma unroll
        for (int n = 0; n < 4; ++n)
            acc[m][n] = (f32x4){0.f, 0.f, 0.f, 0.f};

    long long bfr[4][2];
    long long fa0, fa1, fa2, fa3;

#define LDA_Q(c, q) { fa0 = LD_A(c, 2*(q), 0);   fa1 = LD_A(c, 2*(q), 1);         \
                      fa2 = LD_A(c, 2*(q)+1, 0); fa3 = LD_A(c, 2*(q)+1, 1); }
#define LDB_ALL(c) { _Pragma("unroll") for (int n = 0; n < 4; ++n) {              \
                       bfr[n][0] = LD_B(c, n, 0); bfr[n][1] = LD_B(c, n, 1); } }
#define MFMA_Q(q) { __builtin_amdgcn_s_setprio(1);                                \
    _Pragma("unroll") for (int n = 0; n < 4; ++n) {                               \
      acc[2*(q)][n]   = __builtin_amdgcn_mfma_f32_16x16x32_fp8_fp8(bfr[n][0], fa0, acc[2*(q)][n],   0,0,0); \
      acc[2*(q)][n]   = __builtin_amdgcn_mfma_f32_16x16x32_fp8_fp8(bfr[n][1], fa1, acc[2*(q)][n],   0,0,0); \
      acc[2*(q)+1][n] = __builtin_amdgcn_mfma_f32_16x16x32_fp8_fp8(bfr[n][0], fa2, acc[2*(q)+1][n], 0,0,0); \
      acc[2*(q)+1][n] = __builtin_amdgcn_mfma_f32_16x16x32_fp8_fp8(bfr[n][1], fa3, acc[2*(q)+1][n], 0,0,0); } \
    __builtin_amdgcn_s_setprio(0); }

    // prologue: B(t0) c0,c1; A(t0) c0,c1; B(t1) c0,c1 -> 6 issues; VMC2 -> t0 resident
    STAGE_B(gB, 0, 0, 0); STAGE_B(gB, 0, 1, 0);
    STAGE_A(gA, 0, 0, 0); STAGE_A(gA, 0, 1, 0);
    STAGE_B(gB, 1, 0, 1); STAGE_B(gB, 1, 1, 1);
    VMC2();
    BAR();

    const unsigned char* gAt = gA;   // k-base of tile 2i
    const unsigned char* gBt = gB;
    for (int i = 0; i < 4; ++i) {
        const bool s23 = (i < 3);

        LDA_Q(0, 0); LDB_ALL(0);
        STAGE_A(gAt, 1, 0, 1);
        BAR(); MFMA_Q(0); BAR();

        LDA_Q(0, 1);
        STAGE_A(gAt, 1, 1, 1);
        BAR(); MFMA_Q(1); BAR();

        LDA_Q(0, 2);
        if (s23) STAGE_B(gBt, 0, 0, 2);
        BAR(); MFMA_Q(2); BAR();

        LDA_Q(0, 3);
        if (s23) STAGE_B(gBt, 0, 1, 2);
        BAR(); MFMA_Q(3);
        if (s23) { VMC2(); } else { VMC0(); }
        BAR();

        LDA_Q(1, 0); LDB_ALL(1);
        if (s23) STAGE_A(gAt, 0, 0, 2);
        BAR(); MFMA_Q(0); BAR();

        LDA_Q(1, 1);
        if (s23) STAGE_A(gAt, 0, 1, 2);
        BAR(); MFMA_Q(1); BAR();

        LDA_Q(1, 2);
        if (s23) STAGE_B(gBt, 1, 0, 3);
        BAR(); MFMA_Q(2); BAR();

        LDA_Q(1, 3);
        if (s23) STAGE_B(gBt, 1, 1, 3);
        BAR(); MFMA_Q(3);
        if (s23) { VMC2(); }
        BAR();

        gAt += 128; gBt += 128;   // 2 K-tiles x 64B
    }

    // ---- epilogue: acc(+16*bias) -> swizzled fp8 LDS tile (256x256 = 64 KB) -> C ----
    {
        const int q  = lane >> 4;
        const int tr = wr * 128 + (lane & 15);
        #pragma unroll
        for (int n = 0; n < 4; ++n) {
            float4 bb = *(const float4*)(bias + n0 + wn * 64 + n * 16 + q * 4);
            const int g16 = wn * 4 + n;
            #pragma unroll
            for (int m = 0; m < 8; ++m) {
                const int trm = tr + m * 16;
                unsigned int pk = __builtin_amdgcn_cvt_pk_fp8_f32(
                    acc[m][n][0] + 16.f * bb.x, acc[m][n][1] + 16.f * bb.y, 0u, false);
                pk = __builtin_amdgcn_cvt_pk_fp8_f32(
                    acc[m][n][2] + 16.f * bb.z, acc[m][n][3] + 16.f * bb.w, pk, true);
                *(unsigned int*)(SH + trm * 256 + ((g16 ^ (trm & 15)) << 4) + q * 4) = pk;
            }
        }
        BAR();
        #pragma unroll
        for (int it = 0; it < 8; ++it) {
            const int f = it * 512 + tid;
            const int rr = f >> 4, gg = f & 15;
            uint4 v = *(const uint4*)(SH + rr * 256 + ((gg ^ (rr & 15)) << 4));
            *(uint4*)(C + (size_t)(row0 + rr) * 4096 + gg * 16 + n0) = v;
        }
    }
#undef STAGE_A
#undef STAGE_B
#undef LD_A
#undef LD_B
}

// ---------------- kernel 3: fp8-MFMA scores + softmax + pb-partials ------------------
__global__ __launch_bounds__(256) void mfscores(const unsigned char* __restrict__ Q,
                                                const unsigned char* __restrict__ K,
                                                float* __restrict__ P,
                                                float* __restrict__ pbpart)
{
    __shared__ float Pl[8 * 64];
    const int b = blockIdx.x, lc = blockIdx.y;       // (8, 64)
    const int tid = threadIdx.x, lane = tid & 63, w = tid >> 6;
    const int l0 = lc * 8;

    const int colr = lane & 15;
    const int ko   = lane >> 4;
    const int la   = l0 + w * 2 + (colr >> 3);
    const int hh   = colr & 7;
    const unsigned char* qrow = Q + (size_t)(b * 512 + la) * 4096 + hh * 512 + ko * 8;
    const unsigned char* krow = K + (size_t)(b * 512 + la) * 4096 + hh * 512 + ko * 8;

    f32x4 acc = (f32x4){0.f, 0.f, 0.f, 0.f};
    #pragma unroll
    for (int kt = 0; kt < 16; ++kt) {
        long long av = *(const long long*)(qrow + kt * 32);
        long long bv = *(const long long*)(krow + kt * 32);
        acc = __builtin_amdgcn_mfma_f32_16x16x32_fp8_fp8(av, bv, acc, 0, 0, 0);
    }

    const int lpr = ko >> 1;
    const int lpc = (lane >> 3) & 1;
    #pragma unroll
    for (int r = 0; r < 4; ++r) {
        float s = acc[r] * 1.7263349150062e-4f;   // 1/(256*sqrt(512)) -- Q',K' are x16
        float m = s;
        m = fmaxf(m, __shfl_xor(m, 1));
        m = fmaxf(m, __shfl_xor(m, 2));
        m = fmaxf(m, __shfl_xor(m, 4));
        float e = __expf(s - m);
        float ss = e;
        ss += __shfl_xor(ss, 1);
        ss += __shfl_xor(ss, 2);
        ss += __shfl_xor(ss, 4);
        float p = e / ss + 63.875f;               // fold uniform part
        if (lpr == lpc)
            Pl[(w * 2 + lpr) * 64 + ((ko & 1) * 4 + r) * 8 + (lane & 7)] = p;
    }
    __syncthreads();

    {
        const int l = tid >> 5, off = (tid & 31) * 2;
        float2 v = *(const float2*)&Pl[l * 64 + off];
        *(float2*)(P + (size_t)(b * 512 + l0 + l) * 64 + off) = v;
    }
    if (tid < 64) {
        float s = 0.f;
        #pragma unroll
        for (int l = 0; l < 8; ++l) s += Pl[l * 64 + tid];
        pbpart[((size_t)b * 64 + lc) * 64 + tid] = s;
    }
}

// ---------------- kernel 4: ypart[lc,b,hg,d] = sum_{l in chunk} P' * Xv --------------
__global__ __launch_bounds__(256) void ykern(const float* __restrict__ P,
                                             const float* __restrict__ Xv,
                                             float* __restrict__ ypart)
{
    __shared__ float Pl[128 * 64];
    __shared__ float Xl[128 * 64];
    const int b = blockIdx.x, dt = blockIdx.y, lc = blockIdx.z;
    const int tid = threadIdx.x;
    const int tm = tid & 15, te = tid >> 4;

    const float* Pg = P + ((size_t)b * 512 + lc * 128) * 64;
    #pragma unroll
    for (int i = 0; i < 8; ++i)
        *(float4*)&Pl[(i * 256 + tid) * 4] = *(const float4*)(Pg + (size_t)(i * 256 + tid) * 4);
    const float* Xg = Xv + ((size_t)b * 512 + lc * 128) * 512 + dt * 64;
    #pragma unroll
    for (int i = 0; i < 8; ++i) {
        int flat = i * 256 + tid;
        int r = flat >> 4, q = flat & 15;
        *(float4*)&Xl[r * 64 + q * 4] = *(const float4*)(Xg + (size_t)r * 512 + q * 4);
    }
    __syncthreads();

    float4 acc[4];
    #pragma unroll
    for (int i = 0; i < 4; ++i) acc[i] = make_float4(0.f, 0.f, 0.f, 0.f);

    for (int l = 0; l < 128; ++l) {
        float4 pv = *(const float4*)&Pl[l * 64 + tm * 4];
        float4 xv = *(const float4*)&Xl[l * 64 + te * 4];
        acc[0].x += pv.x * xv.x; acc[0].y += pv.x * xv.y; acc[0].z += pv.x * xv.z; acc[0].w += pv.x * xv.w;
        acc[1].x += pv.y * xv.x; acc[1].y += pv.y * xv.y; acc[1].z += pv.y * xv.z; acc[1].w += pv.y * xv.w;
        acc[2].x += pv.z * xv.x; acc[2].y += pv.z * xv.y; acc[2].z += pv.z * xv.z; acc[2].w += pv.z * xv.w;
        acc[3].x += pv.w * xv.x; acc[3].y += pv.w * xv.y; acc[3].z += pv.w * xv.z; acc[3].w += pv.w * xv.w;
    }
    #pragma unroll
    for (int i = 0; i < 4; ++i)
        *(float4*)&ypart[(((size_t)lc * 8 + b) * 64 + tm * 4 + i) * 512 + dt * 64 + te * 4] = acc[i];
}

// ---------------- kernel 5: split-K vgemm (yreduce fused into A-stage) ---------------
__global__ __launch_bounds__(256) void vgemm(const float* __restrict__ ypart,
                                             const float* __restrict__ Wv,
                                             float* __restrict__ partial)
{
    __shared__ float Al[64 * 64];
    __shared__ float Bl[64 * 64];
    const int et = blockIdx.x, kc = blockIdx.y;
    const int g = kc >> 3, d0 = (kc & 7) * 64, e0 = et * 64;
    const int tid = threadIdx.x;
    const int tm = tid & 15, te = tid >> 4;

    #pragma unroll
    for (int i = 0; i < 4; ++i) {
        int flat = i * 256 + tid;
        int bh = flat >> 4, dq = flat & 15;
        int yrow = (bh >> 3) * 64 + (bh & 7) * 8 + g;
        size_t base = ((size_t)(yrow >> 6) * 64 + (yrow & 63)) * 512 + d0 + dq * 4;
        float4 v = *(const float4*)(ypart + base);
        #pragma unroll
        for (int lc = 1; lc < 4; ++lc) {
            float4 t = *(const float4*)(ypart + (size_t)lc * 262144 + base);
            v.x += t.x; v.y += t.y; v.z += t.z; v.w += t.w;
        }
        *(float4*)&Al[bh * 64 + ((dq ^ (bh >> 2)) << 2)] = v;
    }
    #pragma unroll
    for (int i = 0; i < 4; ++i) {
        int flat = i * 256 + tid;
        int kk = flat >> 4, eq = flat & 15;
        *(float4*)&Bl[kk * 64 + eq * 4] =
            *(const float4*)(Wv + (size_t)(d0 + kk) * 4096 + g * 512 + e0 + eq * 4);
    }
    __syncthreads();

    float4 acc[4];
    #pragma unroll
    for (int j = 0; j < 4; ++j) acc[j] = make_float4(0.f, 0.f, 0.f, 0.f);

    for (int k = 0; k < 64; ++k) {
        float4 b4 = *(const float4*)&Bl[k * 64 + te * 4];
        const int gcol = (((k >> 2) ^ tm) << 2) + (k & 3);
        #pragma unroll
        for (int j = 0; j < 4; ++j) {
            float a = Al[(tm * 4 + j) * 64 + gcol];
            acc[j].x += a * b4.x; acc[j].y += a * b4.y;
            acc[j].z += a * b4.z; acc[j].w += a * b4.w;
        }
    }
    #pragma unroll
    for (int j = 0; j < 4; ++j)
        *(float4*)&partial[(size_t)kc * 32768 + (tm * 4 + j) * 512 + e0 + te * 4] = acc[j];
}

// ---------------- kernel 6: finalize: out = sum_kc partial + sum_g c*bv --------------
__global__ __launch_bounds__(256) void finalize(const float* __restrict__ partial,
                                                const float* __restrict__ pbpart,
                                                const float* __restrict__ bv,
                                                float* __restrict__ out)
{
    __shared__ float csh[8];
    const int blk = blockIdx.x;
    const int tid = threadIdx.x;
    const int b = blk >> 4, h = (blk >> 1) & 7;
    const int e = (blk & 1) * 256 + tid;

    if (tid < 8) {
        float s = 0.f;
        #pragma unroll 8
        for (int lcc = 0; lcc < 64; ++lcc)
            s += pbpart[((size_t)b * 64 + lcc) * 64 + h * 8 + tid];
        csh[tid] = s;
    }
    __syncthreads();

    const int i = ((b * 8 + h) << 9) + e;
    float s = 0.f;
    #pragma unroll
    for (int kc = 0; kc < 64; ++kc) s += partial[(size_t)kc * 32768 + i];
    float bt = 0.f;
    #pragma unroll
    for (int g = 0; g < 8; ++g) bt += csh[g] * bv[g * 512 + e];
    out[i] = s + bt;
}

extern "C" void kernel_launch(void* const* d_in, const int* in_sizes, int n_in,
                              void* d_out, int out_size, void* d_ws, size_t ws_size,
                              hipStream_t stream)
{
    const float* queries = (const float*)d_in[0];
    const float* keys    = (const float*)d_in[1];
    const float* values  = (const float*)d_in[2];
    const float* Wq      = (const float*)d_in[3];
    const float* bq      = (const float*)d_in[4];
    const float* Wk      = (const float*)d_in[5];
    const float* bk      = (const float*)d_in[6];
    const float* Wv      = (const float*)d_in[7];
    const float* bv      = (const float*)d_in[8];

    unsigned char* xq  = (unsigned char*)d_ws;          // 2 MB each
    unsigned char* xk  = xq  + (1u << 21);
    unsigned char* wtq = xk  + (1u << 21);
    unsigned char* wtk = wtq + (1u << 21);
    unsigned char* Q   = wtk + (1u << 21);              // 16 MB each
    unsigned char* Kb  = Q   + (1u << 24);
    float* P      = (float*)(Kb + (1u << 24));
    float* pbpart = P + 262144;
    float* ypart  = pbpart + 32768;
    float* part   = ypart + 4 * 262144;

    prep<<<dim3(2048, 1, 4), 256, 0, stream>>>(queries, keys, xq, xk, Wq, Wk, wtq, wtk);
    gemm_bt256<<<dim3(16, 16, 2), 512, 0, stream>>>(xq, xk, wtq, wtk, bq, bk, Q, Kb);
    mfscores<<<dim3(8, 64), 256, 0, stream>>>(Q, Kb, P, pbpart);
    ykern<<<dim3(8, 8, 4), 256, 0, stream>>>(P, values, ypart);
    vgemm<<<dim3(8, 64), 256, 0, stream>>>(ypart, Wv, part);
    finalize<<<dim3(128), 256, 0, stream>>>(part, pbpart, bv, (float*)d_out);
}